// Round 13
// baseline (94.428 us; speedup 1.0000x reference)
//
#include <hip/hip_runtime.h>
#include <hip/hip_bf16.h>

// Problem constants (from reference)
#define NUM_NEURONS 32768
#define INPUT_SIZE  8192
#define BATCH       512

typedef float f32x4 __attribute__((ext_vector_type(4)));

// ---------------------------------------------------------------------------
// Kernel A: per-neuron softmax over 16 gate weights -> 4 affine coefficients.
// Every logic op is affine in {1, a, b, ab}: out = C0 + Ca*a + Cb*b + Cab*a*b
// ---------------------------------------------------------------------------
__global__ __launch_bounds__(256) void logic_coeff_kernel(
    const float* __restrict__ gw, float4* __restrict__ coeffs)
{
    const int n = blockIdx.x * 256 + threadIdx.x;
    if (n >= NUM_NEURONS) return;
    const float* g = gw + (size_t)n * 16;

    float w[16];
#pragma unroll
    for (int i = 0; i < 16; i += 4) {
        float4 v = *reinterpret_cast<const float4*>(g + i);
        w[i+0] = v.x; w[i+1] = v.y; w[i+2] = v.z; w[i+3] = v.w;
    }
    float m = w[0];
#pragma unroll
    for (int i = 1; i < 16; ++i) m = fmaxf(m, w[i]);
    float s = 0.f;
#pragma unroll
    for (int i = 0; i < 16; ++i) { w[i] = __expf(w[i] - m); s += w[i]; }
    const float inv = 1.0f / s;

    const float C0  = (w[8] + w[9] + w[10] + w[11] + w[12] + w[13] + w[14] + w[15]) * inv;
    const float Ca  = (w[2] + w[3] + w[6] + w[7] - w[8] - w[9] - w[12] - w[13]) * inv;
    const float Cb  = (w[4] + w[5] + w[6] + w[7] - w[8] - w[9] - w[10] - w[11]) * inv;
    const float Cab = (w[1] - w[2] - w[4] - 2.f*w[6] - w[7]
                       + w[8] + 2.f*w[9] + w[11] + w[13] - w[14]) * inv;

    coeffs[n] = make_float4(C0, Ca, Cb, Cab);
}

// ---------------------------------------------------------------------------
// Kernel B: block = (row-pair, neuron-half). 512 threads, 2 blocks/CU.
// LDS layout: PAIRED-ROW interleave in 128-dword blocks:
//   dword d: blk=d>>8, within=d&255; within<128 -> row0[128*blk+within]
//                                    else       -> row1[128*blk+within-128]
// => values of both rows at input index i sit at dwords base and base+128
//    (base = (i&127) + (i>>7)*256) -> ONE fused ds_read2_b32 per index.
// Staged with global_load_lds (linear LDS dest) + PER-LANE global source:
//   lanes 0-31 read row0, lanes 32-63 read row1 (m173 pattern).
// Main loop: fully unrolled, double-buffered coeff/idx prefetch (iter i+1's
// L2 loads issue before iter i's gathers; iter 0's before the barrier),
// wave-staggered slabs, nontemporal f32x4 stores, ONE barrier total.
// ---------------------------------------------------------------------------
constexpr int BLK  = 512;                        // threads per block
constexpr int RPB  = 2;                          // rows per block
constexpr int HALF = NUM_NEURONS / 2;            // 16384 neurons per block
constexpr int QPT  = HALF / 4 / BLK;             // 8 quad-iterations per thread
constexpr int SF4  = RPB * INPUT_SIZE / 4 / BLK; // 8 stage instrs per thread

__global__ __launch_bounds__(BLK, 4) void logic_main_kernel(
    const float*  __restrict__ x,
    const float4* __restrict__ coeffs,
    const int4*   __restrict__ idx4,
    float*        __restrict__ out)
{
    __shared__ float sx[RPB * INPUT_SIZE];       // 64 KiB, paired-row layout

    const int tid  = threadIdx.x;
    const int bid  = blockIdx.x;
    const int rp   = bid & 255;                  // row-pair index
    const int half = bid >> 8;                   // 0 / 1
    const int row0 = rp * RPB;
    const int nh0  = half * HALF;                // neuron-half base
    const int wid  = tid >> 6;                   // wave id 0..7
    const int lane = tid & 63;

    // ---- Stage both rows into paired-row LDS layout via global_load_lds.
    // Stage instr s, wave w writes LDS dwords [2048s+256w .. +255] = block
    // (8s+w): lanes 0-31 supply row0[128*(8s+w) + 4*lane .. +3], lanes
    // 32-63 supply row1[128*(8s+w) + 4*(lane-32) .. +3].
    {
        const float4* xr0 = reinterpret_cast<const float4*>(x + (size_t)row0 * INPUT_SIZE);
        const float4* xr1 = reinterpret_cast<const float4*>(x + (size_t)(row0 + 1) * INPUT_SIZE);
        float4* s4 = reinterpret_cast<float4*>(sx);
#pragma unroll
        for (int s = 0; s < SF4; ++s) {
            const float4* src = ((lane < 32) ? xr0 : xr1) + 32 * (8 * s + wid) + (lane & 31);
            __builtin_amdgcn_global_load_lds(
                (const __attribute__((address_space(1))) void*)src,
                (__attribute__((address_space(3))) void*)(s4 + 512 * s + tid),
                16, 0, 0);
        }
    }

    // ---- Double-buffered coeff/idx metadata. Iter it, this wave's slab:
    // g=(it+wid)&7, quad base nb = nh0 + g*2048 + wid*256 + lane*4.
    float4 c[2][4];
    int4   p[2][2];
    {   // iter-0 prefetch BEFORE the barrier (independent of LDS).
        const int g  = wid & (QPT - 1);
        const int nb = nh0 + g * 2048 + wid * 256 + lane * 4;
#pragma unroll
        for (int j = 0; j < 4; ++j) c[0][j] = coeffs[nb + j];
        p[0][0] = idx4[(nb >> 1) + 0];
        p[0][1] = idx4[(nb >> 1) + 1];
    }

    asm volatile("s_waitcnt vmcnt(0)" ::: "memory");
    __builtin_amdgcn_s_barrier();                // the ONLY barrier

    float* o0 = out + (size_t)row0 * NUM_NEURONS;
    float* o1 = o0 + NUM_NEURONS;

#pragma unroll
    for (int it = 0; it < QPT; ++it) {
        const int cur = it & 1;                  // compile-time after unroll

        // Prefetch next iteration's metadata (hides L2 latency under gathers).
        if (it + 1 < QPT) {
            const int gn  = (it + 1 + wid) & (QPT - 1);
            const int nbn = nh0 + gn * 2048 + wid * 256 + lane * 4;
#pragma unroll
            for (int j = 0; j < 4; ++j) c[cur ^ 1][j] = coeffs[nbn + j];
            p[cur ^ 1][0] = idx4[(nbn >> 1) + 0];
            p[cur ^ 1][1] = idx4[(nbn >> 1) + 1];
        }

        const int g  = (it + wid) & (QPT - 1);
        const int nb = nh0 + g * 2048 + wid * 256 + lane * 4;

        // Paired-row gathers: one ds_read2_b32 pair per input index.
        f32x4 r0, r1;
#pragma unroll
        for (int j = 0; j < 4; ++j) {
            const int ia = (j < 2) ? ((j == 0) ? p[cur][0].x : p[cur][0].z)
                                   : ((j == 2) ? p[cur][1].x : p[cur][1].z);
            const int ib = (j < 2) ? ((j == 0) ? p[cur][0].y : p[cur][0].w)
                                   : ((j == 2) ? p[cur][1].y : p[cur][1].w);
            const int da = (ia & 127) + ((ia >> 7) << 8);
            const int db = (ib & 127) + ((ib >> 7) << 8);
            const float a0 = sx[da], a1 = sx[da + 128];   // fuse: ds_read2_b32
            const float b0 = sx[db], b1 = sx[db + 128];
            const float4 cc = c[cur][j];
            r0[j] = fmaf(a0, fmaf(cc.w, b0, cc.y), fmaf(cc.z, b0, cc.x));
            r1[j] = fmaf(a1, fmaf(cc.w, b1, cc.y), fmaf(cc.z, b1, cc.x));
        }
        __builtin_nontemporal_store(r0, reinterpret_cast<f32x4*>(o0 + nb));
        __builtin_nontemporal_store(r1, reinterpret_cast<f32x4*>(o1 + nb));
    }
}

extern "C" void kernel_launch(void* const* d_in, const int* in_sizes, int n_in,
                              void* d_out, int out_size, void* d_ws, size_t ws_size,
                              hipStream_t stream)
{
    const float* x   = (const float*)d_in[0];   // (512, 8192) f32
    const float* gw  = (const float*)d_in[1];   // (32768, 16) f32
    const int4*  idx = (const int4*)d_in[2];    // (32768, 2) i32, int4 pairs
    float* out = (float*)d_out;                 // (512, 32768) f32

    float4* coeffs = (float4*)d_ws;             // 512 KiB scratch

    logic_coeff_kernel<<<NUM_NEURONS / 256, 256, 0, stream>>>(gw, coeffs);

    // 256 row-pairs x 2 neuron-halves
    logic_main_kernel<<<(BATCH / RPB) * 2, BLK, 0, stream>>>(x, coeffs, idx, out);
}